// Round 1
// baseline (436.778 us; speedup 1.0000x reference)
//
#include <hip/hip_runtime.h>

#define LRELU(v) ((v) > 0.f ? (v) : 0.2f * (v))

__device__ __forceinline__ unsigned int f2o(float f) {
    unsigned int b = __float_as_uint(f);
    return (b & 0x80000000u) ? ~b : (b | 0x80000000u);
}
__device__ __forceinline__ float o2f(unsigned int u) {
    return __uint_as_float((u & 0x80000000u) ? (u ^ 0x80000000u) : ~u);
}
__device__ __forceinline__ float wred(float v) {
#pragma unroll
    for (int m = 1; m < 64; m <<= 1) v += __shfl_xor(v, m);
    return v;
}

// consts layout (floats):
// [0]=cs1 [1]=cd1 [2..65]=va_s(64) [66..129]=va_d(64) [130..257]=bc(128)
// [258..8449]=WcT (64 x 128): WcT[k*128+c] = sum_j Wl2[c][j]*W2[j][k]
#define C_VAS 2
#define C_VAD 66
#define C_BC 130
#define C_WCT 258

__global__ void k0_precompute(const float* W1, const float* as1, const float* ad1,
                              const float* W2, const float* as2, const float* ad2,
                              const float* b2, const float* Wl2, const float* bl2,
                              float* consts) {
    int b = blockIdx.x, t = threadIdx.x;  // blockDim = 128
    if (b < 64) {
        float acc = 0.f;
#pragma unroll 8
        for (int j = 0; j < 128; ++j) acc += Wl2[t * 128 + j] * W2[j * 64 + b];
        consts[C_WCT + b * 128 + t] = acc;
    } else {
        if (t < 64) {
            float vs = 0.f, vd = 0.f;
            for (int c = 0; c < 128; ++c) {
                float w = W2[c * 64 + t];
                vs += as2[c] * w;
                vd += ad2[c] * w;
            }
            consts[C_VAS + t] = vs;
            consts[C_VAD + t] = vd;
        }
        float acc = bl2[t];
        for (int j = 0; j < 128; ++j) acc += Wl2[t * 128 + j] * b2[j];
        consts[C_BC + t] = acc;
        if (t < 64) {
            float p = W1[t] * as1[t], q = W1[t] * ad1[t];
            p = wred(p);
            q = wred(q);
            if (t == 0) { consts[0] = p; consts[1] = q; }
        }
    }
}

__global__ void k1_init_m1(const float* x, const float* consts, unsigned int* m_u, int N) {
    int i = blockIdx.x * blockDim.x + threadIdx.x;
    if (i >= N) return;
    float es = LRELU(x[i] * (consts[0] + consts[1]));
    m_u[i] = f2o(es);
}

__global__ void k2_edge_max1(const int* src, const int* dst, const float* x,
                             const float* consts, float* e1, unsigned int* m_u, int E) {
    int e = blockIdx.x * blockDim.x + threadIdx.x;
    if (e >= E) return;
    int s = src[e], d = dst[e];
    float ev = LRELU(consts[0] * x[s] + consts[1] * x[d]);
    e1[e] = ev;
    atomicMax(&m_u[d], f2o(ev));
}

__global__ void k3_node_self1(const float* x, const float* consts, unsigned int* m_u,
                              float* z, float* agg1, int N) {
    int i = blockIdx.x * blockDim.x + threadIdx.x;
    if (i >= N) return;
    float m = o2f(m_u[i]);
    float es = LRELU(x[i] * (consts[0] + consts[1]));
    float w = __expf(es - m);
    ((float*)m_u)[i] = m;  // overwrite with plain float max
    z[i] = w;
    agg1[i] = w * x[i];
}

__global__ void k4_edge_agg1(const int* src, const int* dst, const float* x,
                             const float* e1, const float* mf, float* z, float* agg1, int E) {
    int e = blockIdx.x * blockDim.x + threadIdx.x;
    if (e >= E) return;
    int s = src[e], d = dst[e];
    float w = __expf(e1[e] - mf[d]);
    atomicAdd(&z[d], w);
    atomicAdd(&agg1[d], w * x[s]);
}

__global__ void k5_node_l1out(const float* consts, const float* W1, const float* b1,
                              const float* agg1, const float* z, float* hrelu,
                              float* a2s, float* a2d, unsigned int* m_u2, int N) {
    int i = blockIdx.x * blockDim.y + threadIdx.y;
    int k = threadIdx.x;
    if (i >= N) return;
    float a1 = agg1[i] / z[i];
    float h = a1 * W1[k] + b1[k];
    h = h > 0.f ? h : 0.f;
    hrelu[(size_t)i * 64 + k] = h;
    float ps = wred(h * consts[C_VAS + k]);
    float pd = wred(h * consts[C_VAD + k]);
    if (k == 0) {
        a2s[i] = ps;
        a2d[i] = pd;
        m_u2[i] = f2o(LRELU(ps + pd));
    }
}

__global__ void k6_edge_max2(const int* src, const int* dst, const float* a2s, const float* a2d,
                             float* e2, unsigned int* m_u, int E) {
    int e = blockIdx.x * blockDim.x + threadIdx.x;
    if (e >= E) return;
    int s = src[e], d = dst[e];
    float ev = LRELU(a2s[s] + a2d[d]);
    e2[e] = ev;
    atomicMax(&m_u[d], f2o(ev));
}

__global__ void k7_node_self2(const float* a2s, const float* a2d, unsigned int* m_u,
                              const float* hrelu, float* z, float* agg2, int N) {
    int i = blockIdx.x * blockDim.y + threadIdx.y;
    int k = threadIdx.x;
    if (i >= N) return;
    float m = o2f(m_u[i]);
    float es = LRELU(a2s[i] + a2d[i]);
    float w = __expf(es - m);
    if (k == 0) {
        ((float*)m_u)[i] = m;
        z[i] = w;
    }
    agg2[(size_t)i * 64 + k] = w * hrelu[(size_t)i * 64 + k];
}

__global__ void k8_edge_agg2(const int* src, const int* dst, const float* e2, const float* mf,
                             const float* hrelu, float* z, float* agg2, int E) {
    int e = blockIdx.x * blockDim.y + threadIdx.y;
    int k = threadIdx.x;
    if (e >= E) return;
    int s = src[e], d = dst[e];
    float w = __expf(e2[e] - mf[d]);
    if (k == 0) atomicAdd(&z[d], w);
    atomicAdd(&agg2[(size_t)d * 64 + k], w * hrelu[(size_t)s * 64 + k]);
}

__global__ void k9_final(const float* x, const float* consts, const float* agg2, const float* z,
                         const float* Wl1, const float* bl1, float* out, int N) {
    __shared__ float sv[4][64];
    int i = blockIdx.x * blockDim.y + threadIdx.y;
    int k = threadIdx.x, wy = threadIdx.y;
    bool ok = (i < N);
    if (ok) {
        float v = agg2[(size_t)i * 64 + k] / z[i];
        sv[wy][k] = v;
    }
    __syncthreads();
    if (!ok) return;
    float acc1 = consts[C_BC + k], acc2 = consts[C_BC + 64 + k];
#pragma unroll 8
    for (int j = 0; j < 64; ++j) {
        float vj = sv[wy][j];
        acc1 += consts[C_WCT + j * 128 + k] * vj;
        acc2 += consts[C_WCT + j * 128 + 64 + k] * vj;
    }
    float xi = x[i];
    out[(size_t)i * 128 + k]      = xi * Wl1[k]      + bl1[k]      + fmaxf(acc1, 0.f);
    out[(size_t)i * 128 + 64 + k] = xi * Wl1[64 + k] + bl1[64 + k] + fmaxf(acc2, 0.f);
}

extern "C" void kernel_launch(void* const* d_in, const int* in_sizes, int n_in,
                              void* d_out, int out_size, void* d_ws, size_t ws_size,
                              hipStream_t stream) {
    const float* x   = (const float*)d_in[0];
    const int*   ei  = (const int*)d_in[1];
    const float* W1  = (const float*)d_in[2];
    const float* as1 = (const float*)d_in[3];
    const float* ad1 = (const float*)d_in[4];
    const float* b1  = (const float*)d_in[5];
    const float* W2  = (const float*)d_in[6];
    const float* as2 = (const float*)d_in[7];
    const float* ad2 = (const float*)d_in[8];
    const float* b2  = (const float*)d_in[9];
    const float* Wl1 = (const float*)d_in[10];
    const float* bl1 = (const float*)d_in[11];
    const float* Wl2 = (const float*)d_in[12];
    const float* bl2 = (const float*)d_in[13];

    int N = in_sizes[0];
    int E = in_sizes[1] / 2;
    const int* srcp = ei;
    const int* dstp = ei + E;

    float* ws = (float*)d_ws;
    float* consts = ws;                       // 8704 floats
    float* mbuf   = ws + 8704;                // N (uint order-map, then float max)
    float* zbuf   = mbuf + N;                 // N
    float* agg1   = zbuf + N;                 // N
    float* a2s    = agg1 + N;                 // N
    float* a2d    = a2s + N;                  // N
    float* ebuf   = a2d + N;                  // E
    float* hrel   = ebuf + E;                 // 64*N
    float* agg2   = hrel + (size_t)64 * N;    // 64*N

    dim3 b256(256);
    dim3 bw(64, 4);

    k0_precompute<<<65, 128, 0, stream>>>(W1, as1, ad1, W2, as2, ad2, b2, Wl2, bl2, consts);
    k1_init_m1<<<(N + 255) / 256, b256, 0, stream>>>(x, consts, (unsigned int*)mbuf, N);
    k2_edge_max1<<<(E + 255) / 256, b256, 0, stream>>>(srcp, dstp, x, consts, ebuf,
                                                       (unsigned int*)mbuf, E);
    k3_node_self1<<<(N + 255) / 256, b256, 0, stream>>>(x, consts, (unsigned int*)mbuf,
                                                        zbuf, agg1, N);
    k4_edge_agg1<<<(E + 255) / 256, b256, 0, stream>>>(srcp, dstp, x, ebuf, mbuf, zbuf, agg1, E);
    k5_node_l1out<<<(N + 3) / 4, bw, 0, stream>>>(consts, W1, b1, agg1, zbuf, hrel, a2s, a2d,
                                                  (unsigned int*)mbuf, N);
    k6_edge_max2<<<(E + 255) / 256, b256, 0, stream>>>(srcp, dstp, a2s, a2d, ebuf,
                                                       (unsigned int*)mbuf, E);
    k7_node_self2<<<(N + 3) / 4, bw, 0, stream>>>(a2s, a2d, (unsigned int*)mbuf, hrel,
                                                  zbuf, agg2, N);
    k8_edge_agg2<<<(E + 3) / 4, bw, 0, stream>>>(srcp, dstp, ebuf, mbuf, hrel, zbuf, agg2, E);
    k9_final<<<(N + 3) / 4, bw, 0, stream>>>(x, consts, agg2, zbuf, Wl1, bl1, (float*)d_out, N);
}